// Round 11
// baseline (436.109 us; speedup 1.0000x reference)
//
#include <hip/hip_runtime.h>
#include <cstdint>
#include <cstddef>

#define NN 8192
#define FIN 256
#define FOUT 128
#define SLOPE 0.2f
#define SHIFT 8.0f

typedef float f32x4 __attribute__((ext_vector_type(4)));
typedef __bf16 bf16x8 __attribute__((ext_vector_type(8)));
typedef int i32x4 __attribute__((ext_vector_type(4)));
typedef unsigned int u32x4 __attribute__((ext_vector_type(4)));

__device__ __forceinline__ unsigned short f2bf(float f) {
  return __builtin_bit_cast(unsigned short, (__bf16)f);
}

// async global->LDS DMA; LDS dest = wave-uniform base + lane*16; per-lane src
__device__ __forceinline__ void async_cp16(void* lds, const void* g) {
  __builtin_amdgcn_global_load_lds(
      (const __attribute__((address_space(1))) void*)g,
      (__attribute__((address_space(3))) void*)lds, 16, 0, 0);
}

// ---------------------------------------------------------------------------
// COLUMN PERMUTATION (v19): within each 64-col window, col c = q*4+e is
// STORED at slot s = e*16+q (ht, FbfF, FbfF2, and adj mask bits all use slot
// order). The attention j-sum is order-invariant, so compute() is unchanged;
// only k_hw's stores and k_gat's adj ballot-extraction know about it.
// Payoff: k_gat's adj loads become 4x dwordx4 (1 KB contiguous per instr,
// 4 rows x 256 B) instead of 16 scalar dwords -> 4x fewer VMEM ops and 4x
// better DRAM page locality on the 268 MB stream.
// ---------------------------------------------------------------------------

// Kernel A: h = x @ W (fp32 acc) -> ht[FOUT][NN] bf16 (transposed, col-
// permuted), fused s-reductions + exp tables (F planes col-permuted).
__global__ __launch_bounds__(256, 4) void k_hw(const float* __restrict__ x,
                                               const float* __restrict__ W,
                                               const float* __restrict__ a1,
                                               const float* __restrict__ a2,
                                               unsigned short* __restrict__ ht,
                                               float* __restrict__ Etab,
                                               unsigned short* __restrict__ FbfF,
                                               unsigned short* __restrict__ FbfF2) {
  __shared__ float xs[8][256];
  __shared__ unsigned short tile[128][8];   // [f][row]
  const int tid = threadIdx.x;
  const int rowbase = blockIdx.x * 8;

  #pragma unroll
  for (int it = 0; it < 2; ++it) {
    int fi = it * 1024 + tid * 4;
    int r = fi >> 8, k = fi & 255;
    *(f32x4*)&xs[r][k] = *(const f32x4*)(x + (size_t)(rowbase + r) * FIN + k);
  }
  __syncthreads();

  const int r = tid >> 5;    // 0..7
  const int cg = tid & 31;   // cols cg*4..cg*4+3
  f32x4 acc = {0.f, 0.f, 0.f, 0.f};

  #pragma unroll 8
  for (int k = 0; k < FIN; ++k) {
    f32x4 wv = *(const f32x4*)(W + k * FOUT + cg * 4);
    float xv = xs[r][k];
    acc[0] += xv * wv[0];
    acc[1] += xv * wv[1];
    acc[2] += xv * wv[2];
    acc[3] += xv * wv[3];
  }

  #pragma unroll
  for (int c = 0; c < 4; ++c) tile[cg * 4 + c][r] = f2bf(acc[c]);

  f32x4 av1 = *(const f32x4*)(a1 + cg * 4);
  f32x4 av2 = *(const f32x4*)(a2 + cg * 4);
  float s1 = acc[0] * av1[0] + acc[1] * av1[1] + acc[2] * av1[2] + acc[3] * av1[3];
  float s2 = acc[0] * av2[0] + acc[1] * av2[1] + acc[2] * av2[2] + acc[3] * av2[3];
  #pragma unroll
  for (int off = 16; off > 0; off >>= 1) {
    s1 += __shfl_xor(s1, off, 64);
    s2 += __shfl_xor(s2, off, 64);
  }
  if (cg == 0) {
    const int row = rowbase + r;
    float c0 = s1 + SHIFT;
    float c = fmaxf(c0, SLOPE * c0);
    Etab[(size_t)row * 2]     = __expf(s1 - c);      // row side: NOT permuted
    Etab[(size_t)row * 2 + 1] = __expf(SLOPE * s1 - c);
    // F planes are j-side: store at permuted slot
    const int cl = row & 63;
    const int fidx = (row & ~63) + (cl & 3) * 16 + (cl >> 2);
    FbfF[fidx]  = f2bf(__expf(s2));
    FbfF2[fidx] = f2bf(__expf(SLOPE * s2));
  }
  __syncthreads();

  // ht store, col-permuted: this block's 8 cols live at slots e*16 + q0(+1),
  // e = r&3. u32 at slot e*16+q0 packs cols (rowbase+e, rowbase+e+4).
  if (tid < 128) {
    const int Wb = rowbase & ~63;
    const int q0 = (rowbase & 63) >> 2;   // even (rowbase % 8 == 0)
    #pragma unroll
    for (int e = 0; e < 4; ++e) {
      unsigned int v = (unsigned int)tile[tid][e] |
                       ((unsigned int)tile[tid][e + 4] << 16);
      *(unsigned int*)(ht + (size_t)tid * NN + Wb + e * 16 + q0) = v;
    }
  }
}

// ---------------------------------------------------------------------------
// Kernel B: fused masked-softmax aggregation, v19.
// Budget (R10): k_gat ~107 us = ~70 structural (measured L2-fed in v14) +
// ~37 additive adj stream. The adj stream's 16 scalar-dword loads/lane give
// 256 B-per-page DRAM locality and 16 VMEM slots -> runs ~2.5 TB/s eff and
// leaks latency into every barrier. v19 = v18 + permuted dwordx4 adj:
//  * 4 dwordx4 loads/lane/chunk, each 1 KB contiguous (rows 4i+(lane>>4),
//    cols (lane&15)*4..+3 of the window).
//  * ballot per int element e: bit L of ballot = (row L>>4, col (L&15)*4+e)
//    = permuted slot e*16+(L&15) -> mask words are direct slices:
//    w0 = b0[16r..+15] | b1[...]<<16 (slots 0..31), w1 = b2|b3 (32..63).
//  * compute(), grid, finish: identical to v18.
// ---------------------------------------------------------------------------
__global__ __launch_bounds__(512, 4) void k_gat(const int* __restrict__ adj,
                                                const unsigned short* __restrict__ ht,
                                                const float* __restrict__ Etab,
                                                const unsigned short* __restrict__ FbfF,
                                                const unsigned short* __restrict__ FbfF2,
                                                float* __restrict__ part,
                                                float* __restrict__ denp) {
  __shared__ unsigned short sH[2][128 * 64]; // 32 KB : ht slots, group s^(f&7)
  __shared__ unsigned int sAp[2][128][2];    // 2 KB  : [buf][local row][word]
  __shared__ unsigned short sF[2][128];      // 512 B : [0,64)=F, [64,128)=F2

  const int tid = threadIdx.x;
  const int wave = tid >> 6;                 // 0..7, owns rows 16w..16w+15
  const int lane = tid & 63;
  const int quad = lane >> 4;
  const int m = lane & 15;                   // A-row label within wave's 16
  const int rowbase = (int)(blockIdx.x >> 4) * 128;
  const int CB = (int)(blockIdx.x & 15);
  const int colbase = CB * 512;
  const int row = rowbase + wave * 16 + m;

  // ---- runtime layout probes (exact in bf16/fp32) ----
  bf16x8 pm, pinv, pones;
  #pragma unroll
  for (int jj = 0; jj < 8; ++jj) {
    pm[jj] = (__bf16)(float)m;
    pinv[jj] = (__bf16)0.03125f;
    pones[jj] = (__bf16)1.0f;
  }
  f32x4 z = {0.f, 0.f, 0.f, 0.f};
  f32x4 rp = __builtin_amdgcn_mfma_f32_16x16x32_bf16(pm, pinv, z, 0, 0, 0);
  f32x4 cp = __builtin_amdgcn_mfma_f32_16x16x32_bf16(pinv, pm, z, 0, 0, 0);
  int rowmap[4], colmap[4];
  #pragma unroll
  for (int r = 0; r < 4; ++r) {
    rowmap[r] = ((int)(rp[r] + 0.5f)) & 15;
    colmap[r] = ((int)(cp[r] + 0.5f)) & 15;
  }

  const float E  = Etab[(size_t)row * 2];
  const float E2 = Etab[(size_t)row * 2 + 1];

  f32x4 acc[8];
  #pragma unroll
  for (int t = 0; t < 8; ++t) acc[t] = z;
  f32x4 den = z;

  // ---- adj: 4x dwordx4 per chunk; instr i covers rows 4i..4i+3 ----
  const int* adjBase = adj + (size_t)(rowbase + wave * 16 + (lane >> 4)) * NN +
                       colbase + (lane & 15) * 4;
  i32x4 abuf[4];
  auto loadA = [&](int c) {
    #pragma unroll
    for (int i = 0; i < 4; ++i)
      abuf[i] = *(const i32x4*)(adjBase + (size_t)(i * 4) * NN + c * 64);
  };
  auto packA = [&](int b) {
    const int sh = (lane & 3) * 16;
    #pragma unroll
    for (int i = 0; i < 4; ++i) {
      const unsigned long long b0 = __ballot(abuf[i][0] != 0);
      const unsigned long long b1 = __ballot(abuf[i][1] != 0);
      const unsigned long long b2 = __ballot(abuf[i][2] != 0);
      const unsigned long long b3 = __ballot(abuf[i][3] != 0);
      const unsigned int w0 = (unsigned int)(((b0 >> sh) & 0xFFFFull) |
                                             (((b1 >> sh) & 0xFFFFull) << 16));
      const unsigned int w1 = (unsigned int)(((b2 >> sh) & 0xFFFFull) |
                                             (((b3 >> sh) & 0xFFFFull) << 16));
      if (lane < 4) {
        sAp[b][wave * 16 + i * 4 + lane][0] = w0;
        sAp[b][wave * 16 + i * 4 + lane][1] = w1;
      }
    }
  };

  // ---- ht / F DMA source pointers (storage already permuted -> linear) ----
  const unsigned short* srcH[2];
  #pragma unroll
  for (int il = 0; il < 2; ++il) {
    const int i = wave * 2 + il;
    const int f = i * 8 + (lane >> 3);
    const int g = (lane & 7) ^ (lane >> 3);
    srcH[il] = ht + (size_t)f * NN + colbase + g * 8;
  }
  const unsigned short* srcF = nullptr;
  if (wave == 1) {
    srcF = (lane < 8) ? (FbfF + colbase + lane * 8)
                      : (FbfF2 + colbase + (lane - 8) * 8);
  }

  auto stage = [&](int b, int c) {
    #pragma unroll
    for (int il = 0; il < 2; ++il)
      async_cp16(&sH[b][(wave * 2 + il) * 512], srcH[il] + c * 64);
    if (wave == 1 && lane < 16) async_cp16(&sF[b][0], srcF + c * 64);
  };

  auto compute = [&](int cs) {
    #pragma unroll
    for (int k32 = 0; k32 < 2; ++k32) {
      const unsigned int word = sAp[cs][wave * 16 + m][k32];
      const unsigned int byt = (word >> (quad * 8)) & 0xffu;
      const int jl = k32 * 32 + quad * 8;
      u32x4 Fq = *(const u32x4*)&sF[cs][jl];        // 8 bf16 F (slot order)
      u32x4 Gq = *(const u32x4*)&sF[cs][64 + jl];   // 8 bf16 F2

      bf16x8 af;
      #pragma unroll
      for (int p = 0; p < 4; ++p) {
        const unsigned fp = Fq[p], gp = Gq[p];
        const float Flo = __builtin_bit_cast(float, fp << 16);
        const float Fhi = __builtin_bit_cast(float, fp & 0xffff0000u);
        const float Glo = __builtin_bit_cast(float, gp << 16);
        const float Ghi = __builtin_bit_cast(float, gp & 0xffff0000u);
        const float wlo = fmaxf(E * Flo, E2 * Glo);
        const float whi = fmaxf(E * Fhi, E2 * Ghi);
        af[p * 2]     = (byt & (1u << (p * 2)))     ? (__bf16)wlo : (__bf16)0.0f;
        af[p * 2 + 1] = (byt & (1u << (p * 2 + 1))) ? (__bf16)whi : (__bf16)0.0f;
      }

      // ht frags: tile t, slot-group s = (4k32+quad) ^ (m&7); same af, 8 t
      const int s0 = (k32 * 4 + quad) ^ (m & 7);
      #pragma unroll
      for (int t = 0; t < 8; ++t) {
        bf16x8 bt = __builtin_bit_cast(bf16x8,
            *(const u32x4*)&sH[cs][(t * 16 + m) * 64 + s0 * 8]);
        acc[t] = __builtin_amdgcn_mfma_f32_16x16x32_bf16(af, bt, acc[t], 0, 0, 0);
      }
      den = __builtin_amdgcn_mfma_f32_16x16x32_bf16(af, pones, den, 0, 0, 0);
    }
  };

  // ---- prologue: pack chunk 0, preload regs for chunk 1, DMA chunk 0 ----
  loadA(0);       // compiler inserts the vmcnt wait before the ballots
  packA(0);
  loadA(1);
  stage(0, 0);

  // 8 chunks of 64 cols over this block's 512-col sixteenth; per phase:
  // barrier (drains DMA(c) + loads(c+1)) -> ballots(c+1) -> issue loads(c+2)
  // early -> DMA(c+1) -> compute(c).
  #pragma unroll 1
  for (int c = 0; c < 8; ++c) {
    const int cs = c & 1, ns = cs ^ 1;
    __syncthreads();
    if (c + 1 < 8) {
      packA(ns);                          // regs -> sAp[ns] (chunk c+1)
      loadA(c + 2 < 8 ? c + 2 : 7);       // issue next loads (dead at tail)
      stage(ns, c + 1);                   // ht/F DMA chunk c+1
    }
    compute(cs);                          // chunk c
  }

  // ---- epilogue: coalesced partial stores via LDS bounce (NO atomics) ----
  float* sOut = (float*)&sH[0][0];   // 32 KB = 128 rows x 64 cols fp32
  #pragma unroll
  for (int h = 0; h < 2; ++h) {
    __syncthreads();                 // sH readers done / previous half stored
    #pragma unroll
    for (int r = 0; r < 4; ++r) {
      #pragma unroll
      for (int tt = 0; tt < 4; ++tt) {
        sOut[(wave * 16 + rowmap[r]) * 64 + tt * 16 + colmap[r]] =
            acc[h * 4 + tt][r];
      }
    }
    __syncthreads();
    #pragma unroll
    for (int i = 0; i < 4; ++i) {
      const int v = i * 512 + tid;          // f32x4 index, 2048 total
      const int rl = v >> 4, c4 = v & 15;   // 16 f32x4 per 64-col row
      *(f32x4*)&part[((size_t)CB * NN + rowbase + rl) * FOUT + h * 64 + c4 * 4] =
          ((const f32x4*)sOut)[v];
    }
  }
  // den partials: plain stores
  if (m == 0) {
    #pragma unroll
    for (int r = 0; r < 4; ++r)
      denp[(size_t)CB * NN + rowbase + wave * 16 + rowmap[r]] = den[r];
  }
}

// ---------------------------------------------------------------------------
// k_fin: out = (sum_cb part) / (sum_cb denp) + bias   (16 partials)
// ---------------------------------------------------------------------------
__global__ __launch_bounds__(256) void k_fin(const float* __restrict__ part,
                                             const float* __restrict__ denp,
                                             const float* __restrict__ bias,
                                             float* __restrict__ out) {
  const int i4 = blockIdx.x * 256 + threadIdx.x;  // f32x4 index over out
  const int rowi = i4 >> 5;                       // 32 f32x4 per row
  const int f = (i4 & 31) * 4;
  float den = 0.f;
  f32x4 s = {0.f, 0.f, 0.f, 0.f};
  #pragma unroll
  for (int cb = 0; cb < 16; ++cb) {
    den += denp[(size_t)cb * NN + rowi];
    f32x4 p = *(const f32x4*)&part[((size_t)cb * NN + rowi) * FOUT + f];
    s[0] += p[0]; s[1] += p[1]; s[2] += p[2]; s[3] += p[3];
  }
  const float inv = 1.0f / den;
  f32x4 b = *(const f32x4*)(bias + f);
  f32x4 v = {s[0] * inv + b[0], s[1] * inv + b[1],
             s[2] * inv + b[2], s[3] * inv + b[3]};
  *(f32x4*)(out + (size_t)rowi * FOUT + f) = v;
}

// ---------------------------------------------------------------------------
extern "C" void kernel_launch(void* const* d_in, const int* in_sizes, int n_in,
                              void* d_out, int out_size, void* d_ws, size_t ws_size,
                              hipStream_t stream) {
  const float* x    = (const float*)d_in[0];
  const int*   adj  = (const int*)d_in[1];
  const float* W    = (const float*)d_in[2];
  const float* a1   = (const float*)d_in[3];
  const float* a2   = (const float*)d_in[4];
  const float* bias = (const float*)d_in[5];
  float* out = (float*)d_out;

  char* ws = (char*)d_ws;
  unsigned short* ht = (unsigned short*)ws;                            // 2 MB
  float* Etab = (float*)(ws + (size_t)2 * 1024 * 1024);                // 64 KB
  unsigned short* FbfF =
      (unsigned short*)(ws + (size_t)2 * 1024 * 1024 + 64 * 1024);     // 16 KB
  unsigned short* FbfF2 = FbfF + NN;                                   // 16 KB
  float* part = (float*)(ws + (size_t)4 * 1024 * 1024);                // 64 MB
  float* denp = (float*)(ws + (size_t)68 * 1024 * 1024);               // 512 KB

  k_hw<<<NN / 8, 256, 0, stream>>>(x, W, a1, a2, ht, Etab, FbfF, FbfF2);
  k_gat<<<1024, 512, 0, stream>>>(adj, ht, Etab, FbfF, FbfF2, part, denp);
  k_fin<<<(NN * FOUT / 4) / 256, 256, 0, stream>>>(part, denp, bias, out);
}